// Round 7
// baseline (346.038 us; speedup 1.0000x reference)
//
#include <hip/hip_runtime.h>
#include <hip/hip_bf16.h>

// NT-Xent loss: B=4096, D=128, TEMP=0.5, N2=8192.
// loss = mean_i [ log sum_{j!=i} exp(2*sim_ij) - 2*pos_i ]
// sim = zn zn^T (bf16 MFMA), pos_i = fp32 cosine(z_i, z_{i^B}).
// Self-diagonal handled by rowsum init = -exp2(sii_scaled).
//
// R7: R6 (barrier thinning) was neutral -> stalls are latency, not
// barriers. Suspect: VGPR growth in R5/R6 (prefetch+staging regs, no
// min-waves bound) silently dropped waves/SIMD below 4 and broke the
// 4-blocks/CU co-residency. Fix: __launch_bounds__(256,4) pins VGPR<=128,
// 1024 blocks fit 4/CU in one pass. Also: finalize fused into sim via
// panel counters (norm kernel zeroes them; stream order guarantees init),
// removing one dispatch + gap.

#define BB 4096
#define N2 8192
#define DD 128
#define CSPLIT 32          // column splits (grid.x)
#define CW (N2 / CSPLIT)   // 256 cols per block
#define TW 64              // cols staged per round (4 col-tiles, 16 KB)
#define NRD (CW / TW)      // 4 rounds
#define NPANEL 32          // row panels (grid.y)
#define NBLOCKS (CSPLIT * NPANEL)

// sqrt(2*log2(e)): zn scaled by this => A.B = 2*log2(e)*sim, so
// exp(2*sim) = exp2(A.B) directly.
#define SCALE 1.69864360f

#if __has_builtin(__builtin_amdgcn_exp2f)
#define EXP2F(x) __builtin_amdgcn_exp2f(x)
#else
#define EXP2F(x) __expf((x) * 0.6931471805599453f)
#endif

using bf16 = __hip_bfloat16;
typedef __attribute__((ext_vector_type(8))) short short8;   // MFMA A/B frag
typedef __attribute__((ext_vector_type(4))) float float4v;  // MFMA C/D frag

// ---------------- Kernel 1: per-pair normalize, scale, cast bf16 ----------
__global__ __launch_bounds__(256) void ntx_norm_kernel(
    const float* __restrict__ zi, const float* __restrict__ zj,
    bf16* __restrict__ zn, float* __restrict__ rowsum, float* __restrict__ pos,
    float* __restrict__ accum, unsigned int* __restrict__ panelCnt,
    unsigned int* __restrict__ globalCnt) {
  const int wave = threadIdx.x >> 6;
  const int lane = threadIdx.x & 63;
  // zero the sim kernel's completion counters (stream order makes this
  // visible before any sim block runs; ws is re-poisoned every replay)
  if (blockIdx.x == 0 && threadIdx.x < 34) {
    if (threadIdx.x < 32) panelCnt[threadIdx.x] = 0u;
    else if (threadIdx.x == 32) *globalCnt = 0u;
    else *accum = 0.0f;
  }
  const int pair = blockIdx.x * 4 + wave;   // 1024 blocks, 4 pairs/block
  float2 v = ((const float2*)(zi + (size_t)pair * DD))[lane];
  float2 w = ((const float2*)(zj + (size_t)pair * DD))[lane];
  float s1 = v.x * v.x + v.y * v.y;
  float s2 = w.x * w.x + w.y * w.y;
  float s3 = v.x * w.x + v.y * w.y;
  #pragma unroll
  for (int o = 32; o > 0; o >>= 1) {
    s1 += __shfl_xor(s1, o);
    s2 += __shfl_xor(s2, o);
    s3 += __shfl_xor(s3, o);
  }
  float nv = fmaxf(sqrtf(s1), 1e-8f);
  float nw = fmaxf(sqrtf(s2), 1e-8f);
  float rv = SCALE / nv, rw = SCALE / nw;   // scale folded into zn
  bf16 bx = __float2bfloat16(v.x * rv);
  bf16 by = __float2bfloat16(v.y * rv);
  bf16 cx = __float2bfloat16(w.x * rw);
  bf16 cy = __float2bfloat16(w.y * rw);
  __hip_bfloat162 h2; h2.x = bx; h2.y = by;
  __hip_bfloat162 g2; g2.x = cx; g2.y = cy;
  ((__hip_bfloat162*)(zn + (size_t)pair * DD))[lane] = h2;
  ((__hip_bfloat162*)(zn + (size_t)(pair + BB) * DD))[lane] = g2;
  // self-dot in the SAME scaled bf16 precision the MFMA will see
  float fx = __bfloat162float(bx), fy = __bfloat162float(by);
  float gx = __bfloat162float(cx), gy = __bfloat162float(cy);
  float sii = fx * fx + fy * fy;            // = 2log2e * sim_ii (scaled)
  float sjj = gx * gx + gy * gy;
  #pragma unroll
  for (int o = 32; o > 0; o >>= 1) {
    sii += __shfl_xor(sii, o);
    sjj += __shfl_xor(sjj, o);
  }
  if (lane == 0) {
    float c = s3 / (nv * nw);               // fp32 positive-pair cosine
    rowsum[pair]      = -EXP2F(sii);        // cancels diagonal term
    rowsum[pair + BB] = -EXP2F(sjj);
    pos[pair]      = c;
    pos[pair + BB] = c;
  }
}

// ---------------- Kernel 2: fused sim + sum-exp + finalize -----------------
// grid (CSPLIT=32, 32). Block 256 = 4 waves; wave owns 64 rows (4 row-tiles),
// block owns 256 rows x 256 cols. Per round: stage 64 cols (16 KB) of B into
// the spare LDS buffer (coalesced, pre-swizzled source, loads issued EARLY),
// compute 4 col-tiles from the current buffer, ONE barrier, flip.
// Tail: panel-last block finalizes its 256 rows; global-last writes out.
__global__ __launch_bounds__(256, 4) void ntx_sim_kernel(
    const bf16* __restrict__ zn, float* __restrict__ rowsum,
    const float* __restrict__ pos, float* __restrict__ accum,
    unsigned int* __restrict__ panelCnt, unsigned int* __restrict__ globalCnt,
    float* __restrict__ out) {
  const int tid  = threadIdx.x;
  const int wave = tid >> 6;
  const int lane = tid & 63;
  const int quad = lane >> 4;
  const int l15  = lane & 15;
  const char* zb  = (const char*)zn;
  const short* zs = (const short*)zn;

  __shared__ float4 lds[2][TW * 16];   // 2 x 16 KB double buffer
  __shared__ float psm[4];
  __shared__ unsigned int lastPanel;

  const int rowBase  = blockIdx.y * 256 + wave * 64;
  const int colBase0 = blockIdx.x * CW;

  // Staging map: 1024 chunks of 16B per round; thread owns chunks
  // tid + q*256 (q=0..3). Chunk p: col-row g = p>>4, slot = p&15.
  // LDS[g][slot] holds global chunk (slot ^ (g&7)) of col-row g
  // -> swizzled ds_read_b128 is uniform 8 dwords/bank (optimal).
  const int g0 = tid >> 4;
  const int sw = ((tid & 15) ^ (g0 & 7)) << 4;
  const char* srcb = zb + (size_t)(colBase0 + g0) * 256 + sw;

  // prologue: stage round 0
  float4 p0 = *(const float4*)(srcb);
  float4 p1 = *(const float4*)(srcb + 4096);
  float4 p2 = *(const float4*)(srcb + 8192);
  float4 p3 = *(const float4*)(srcb + 12288);

  // A fragments: 4 row-tiles x 4 K-chunks (64 VGPRs) — full-line reads
  short8 a[4][4];
  #pragma unroll
  for (int t = 0; t < 4; t++) {
    const short* ap = zs + (size_t)(rowBase + t * 16 + l15) * DD + quad * 8;
    #pragma unroll
    for (int c = 0; c < 4; c++) a[t][c] = *(const short8*)(ap + c * 32);
  }

  float rs[4][4];
  #pragma unroll
  for (int t = 0; t < 4; t++)
    #pragma unroll
    for (int r = 0; r < 4; r++) rs[t][r] = 0.0f;

  lds[0][tid] = p0;
  lds[0][tid + 256] = p1;
  lds[0][tid + 512] = p2;
  lds[0][tid + 768] = p3;
  __syncthreads();

  int cur = 0;
  #pragma unroll 1
  for (int rd = 0; rd < NRD; rd++) {
    // issue next round's loads EARLY — latency hides under this round
    float4 t0, t1, t2, t3;
    const bool pf = (rd + 1 < NRD);
    if (pf) {
      const char* sb = srcb + (size_t)(rd + 1) * (TW * 256);
      t0 = *(const float4*)(sb);
      t1 = *(const float4*)(sb + 4096);
      t2 = *(const float4*)(sb + 8192);
      t3 = *(const float4*)(sb + 12288);
    }

    const char* lb = (const char*)&lds[cur][0];
    #pragma unroll
    for (int k = 0; k < 4; k++) {           // 4 col-tiles per round
      short8 b[4];
      #pragma unroll
      for (int c = 0; c < 4; c++) {
        const int off = k * 4096 + l15 * 256 +
                        ((((c * 4 + quad) ^ (l15 & 7))) << 4);
        b[c] = *(const short8*)(lb + off);
      }
      #pragma unroll
      for (int t = 0; t < 4; t++) {
        float4v acc = {0.f, 0.f, 0.f, 0.f};
        acc = __builtin_amdgcn_mfma_f32_16x16x32_bf16(a[t][0], b[0], acc, 0, 0, 0);
        acc = __builtin_amdgcn_mfma_f32_16x16x32_bf16(a[t][1], b[1], acc, 0, 0, 0);
        acc = __builtin_amdgcn_mfma_f32_16x16x32_bf16(a[t][2], b[2], acc, 0, 0, 0);
        acc = __builtin_amdgcn_mfma_f32_16x16x32_bf16(a[t][3], b[3], acc, 0, 0, 0);
        // C/D: col = l15, row = quad*4 + r [m89/m91]; acc = 2log2e*sim.
        #pragma unroll
        for (int r = 0; r < 4; r++) rs[t][r] += EXP2F(acc[r]);
      }
    }

    if (pf) {
      // write buf[cur^1]: safe — every wave passed the previous barrier,
      // so all reads of buf[cur^1] (round rd-1) completed. One barrier.
      lds[cur ^ 1][tid] = t0;
      lds[cur ^ 1][tid + 256] = t1;
      lds[cur ^ 1][tid + 512] = t2;
      lds[cur ^ 1][tid + 768] = t3;
      __syncthreads();
      cur ^= 1;
    }
  }

  // reduce across the 16 lanes sharing each row, then one atomic each
  #pragma unroll
  for (int t = 0; t < 4; t++) {
    #pragma unroll
    for (int r = 0; r < 4; r++) {
      float s = rs[t][r];
      s += __shfl_xor(s, 1);
      s += __shfl_xor(s, 2);
      s += __shfl_xor(s, 4);
      s += __shfl_xor(s, 8);
      if (l15 == 0)
        atomicAdd(&rowsum[rowBase + t * 16 + quad * 4 + r], s);
    }
  }

  // ---- fused finalize ----
  __threadfence();                       // rowsum atomics visible
  if (tid == 0) lastPanel = atomicAdd(&panelCnt[blockIdx.y], 1u);
  __syncthreads();
  if (lastPanel == CSPLIT - 1) {
    // last block of this 256-row panel: finalize its rows
    const int r = blockIdx.y * 256 + tid;
    float rsv  = atomicAdd(&rowsum[r], 0.0f);   // coherent read
    float v = __logf(rsv) - 2.0f * pos[r];
    #pragma unroll
    for (int o = 32; o > 0; o >>= 1) v += __shfl_xor(v, o);
    if (lane == 0) psm[wave] = v;
    __syncthreads();
    if (tid == 0) {
      atomicAdd(accum, psm[0] + psm[1] + psm[2] + psm[3]);
    }
  }
  __threadfence();
  if (tid == 0) {
    unsigned int g = atomicAdd(globalCnt, 1u);
    if (g == NBLOCKS - 1) {              // last block overall
      out[0] = atomicAdd(accum, 0.0f) / (float)N2;
    }
  }
}

extern "C" void kernel_launch(void* const* d_in, const int* in_sizes, int n_in,
                              void* d_out, int out_size, void* d_ws, size_t ws_size,
                              hipStream_t stream) {
  const float* zi = (const float*)d_in[0];
  const float* zj = (const float*)d_in[1];
  float* out = (float*)d_out;

  char* ws = (char*)d_ws;
  bf16* zn = (bf16*)ws;                                   // 8192*128*2 = 2 MB
  float* rowsum = (float*)(ws + (size_t)N2 * DD * 2);     // 32 KB
  float* pos = rowsum + N2;                               // 32 KB
  float* accum = pos + N2;                                // 4 B
  unsigned int* panelCnt = (unsigned int*)(accum + 1);    // 128 B
  unsigned int* globalCnt = panelCnt + NPANEL;            // 4 B

  ntx_norm_kernel<<<BB / 4, 256, 0, stream>>>(zi, zj, zn, rowsum, pos,
                                              accum, panelCnt, globalCnt);
  dim3 grid(CSPLIT, NPANEL);
  ntx_sim_kernel<<<grid, 256, 0, stream>>>(zn, rowsum, pos, accum,
                                           panelCnt, globalCnt, out);
}

// Round 9
// 314.611 us; speedup vs baseline: 1.0999x; 1.0999x over previous
//
#include <hip/hip_runtime.h>
#include <hip/hip_bf16.h>

// NT-Xent loss: B=4096, D=128, TEMP=0.5, N2=8192.
// loss = mean_i [ log sum_{j!=i} exp(2*sim_ij) - 2*pos_i ]
// sim = zn zn^T (bf16 MFMA), pos_i = fp32 cosine(z_i, z_{i^B}).
// Self-diagonal handled by rowsum init = -exp2(sii_scaled).
//
// R9: R8 failed to COMPILE ("unsupported expression in static
// initializer: addrspacecast"): the char* buf[2] = {&lds..} pointer array
// forced a static initializer with an LDS addrspacecast. Fix: compute
// buffer bases inline ((char*)lds + cur*16384). Theory unchanged from R8:
// global_load_lds staging (linear LDS dest, pre-swizzled global src, m173
// pattern) kills the 16 always-live prefetch VGPRs -> (256,4) fits without
// spill -> 4 blocks/CU, 1024 blocks in one pass, async prefetch drained
// by the end-of-round barrier. Finalize stays fused (R7-proven).

#define BB 4096
#define N2 8192
#define DD 128
#define CSPLIT 32          // column splits (grid.x)
#define CW (N2 / CSPLIT)   // 256 cols per block
#define TW 64              // cols staged per round (4 col-tiles, 16 KB)
#define NRD (CW / TW)      // 4 rounds
#define NPANEL 32          // row panels (grid.y)
#define NBLOCKS (CSPLIT * NPANEL)
#define BUFBYTES (TW * 16 * 16)   // 16384 B per LDS buffer

// sqrt(2*log2(e)): zn scaled by this => A.B = 2*log2(e)*sim, so
// exp(2*sim) = exp2(A.B) directly.
#define SCALE 1.69864360f

#if __has_builtin(__builtin_amdgcn_exp2f)
#define EXP2F(x) __builtin_amdgcn_exp2f(x)
#else
#define EXP2F(x) __expf((x) * 0.6931471805599453f)
#endif

using bf16 = __hip_bfloat16;
typedef __attribute__((ext_vector_type(8))) short short8;   // MFMA A/B frag
typedef __attribute__((ext_vector_type(4))) float float4v;  // MFMA C/D frag

// async 16B global->LDS (gfx950: global_load_lds_dwordx4).
// LDS dest is wave-uniform base + lane*16; global src is per-lane.
__device__ __forceinline__ void gl_lds16(const char* g, char* ldst) {
  __builtin_amdgcn_global_load_lds(
      (const __attribute__((address_space(1))) void*)g,
      (__attribute__((address_space(3))) void*)ldst, 16, 0, 0);
}

// ---------------- Kernel 1: per-pair normalize, scale, cast bf16 ----------
__global__ __launch_bounds__(256) void ntx_norm_kernel(
    const float* __restrict__ zi, const float* __restrict__ zj,
    bf16* __restrict__ zn, float* __restrict__ rowsum, float* __restrict__ pos,
    float* __restrict__ accum, unsigned int* __restrict__ panelCnt,
    unsigned int* __restrict__ globalCnt) {
  const int wave = threadIdx.x >> 6;
  const int lane = threadIdx.x & 63;
  // zero the sim kernel's completion counters (stream order makes this
  // visible before any sim block runs; ws is re-poisoned every replay)
  if (blockIdx.x == 0 && threadIdx.x < 34) {
    if (threadIdx.x < 32) panelCnt[threadIdx.x] = 0u;
    else if (threadIdx.x == 32) *globalCnt = 0u;
    else *accum = 0.0f;
  }
  const int pair = blockIdx.x * 4 + wave;   // 1024 blocks, 4 pairs/block
  float2 v = ((const float2*)(zi + (size_t)pair * DD))[lane];
  float2 w = ((const float2*)(zj + (size_t)pair * DD))[lane];
  float s1 = v.x * v.x + v.y * v.y;
  float s2 = w.x * w.x + w.y * w.y;
  float s3 = v.x * w.x + v.y * w.y;
  #pragma unroll
  for (int o = 32; o > 0; o >>= 1) {
    s1 += __shfl_xor(s1, o);
    s2 += __shfl_xor(s2, o);
    s3 += __shfl_xor(s3, o);
  }
  float nv = fmaxf(sqrtf(s1), 1e-8f);
  float nw = fmaxf(sqrtf(s2), 1e-8f);
  float rv = SCALE / nv, rw = SCALE / nw;   // scale folded into zn
  bf16 bx = __float2bfloat16(v.x * rv);
  bf16 by = __float2bfloat16(v.y * rv);
  bf16 cx = __float2bfloat16(w.x * rw);
  bf16 cy = __float2bfloat16(w.y * rw);
  __hip_bfloat162 h2; h2.x = bx; h2.y = by;
  __hip_bfloat162 g2; g2.x = cx; g2.y = cy;
  ((__hip_bfloat162*)(zn + (size_t)pair * DD))[lane] = h2;
  ((__hip_bfloat162*)(zn + (size_t)(pair + BB) * DD))[lane] = g2;
  // self-dot in the SAME scaled bf16 precision the MFMA will see
  float fx = __bfloat162float(bx), fy = __bfloat162float(by);
  float gx = __bfloat162float(cx), gy = __bfloat162float(cy);
  float sii = fx * fx + fy * fy;            // = 2log2e * sim_ii (scaled)
  float sjj = gx * gx + gy * gy;
  #pragma unroll
  for (int o = 32; o > 0; o >>= 1) {
    sii += __shfl_xor(sii, o);
    sjj += __shfl_xor(sjj, o);
  }
  if (lane == 0) {
    float c = s3 / (nv * nw);               // fp32 positive-pair cosine
    rowsum[pair]      = -EXP2F(sii);        // cancels diagonal term
    rowsum[pair + BB] = -EXP2F(sjj);
    pos[pair]      = c;
    pos[pair + BB] = c;
  }
}

// ---------------- Kernel 2: fused sim + sum-exp + finalize -----------------
// grid (CSPLIT=32, 32). Block 256 = 4 waves; wave owns 64 rows (4 row-tiles),
// block owns 256 rows x 256 cols. Per round: issue async global_load_lds of
// the next 64 cols (16 KB) into the spare buffer, compute 4 col-tiles from
// the current buffer, ONE barrier (drains vmcnt), flip.
// Tail: panel-last block finalizes its 256 rows; global-last writes out.
__global__ __launch_bounds__(256, 4) void ntx_sim_kernel(
    const bf16* __restrict__ zn, float* __restrict__ rowsum,
    const float* __restrict__ pos, float* __restrict__ accum,
    unsigned int* __restrict__ panelCnt, unsigned int* __restrict__ globalCnt,
    float* __restrict__ out) {
  const int tid  = threadIdx.x;
  const int wave = tid >> 6;
  const int lane = tid & 63;
  const int quad = lane >> 4;
  const int l15  = lane & 15;
  const char* zb  = (const char*)zn;
  const short* zs = (const short*)zn;

  __shared__ float4 lds[2][TW * 16];   // 2 x 16 KB double buffer
  __shared__ float psm[4];
  __shared__ unsigned int lastPanel;

  const int rowBase  = blockIdx.y * 256 + wave * 64;
  const int colBase0 = blockIdx.x * CW;

  // Staging map: 1024 chunks of 16B per round; chunk c lives at LDS byte
  // c*16 and holds global 16B-chunk (slot ^ (g&7)) of col-row g (g = c>>4,
  // slot = c&15) -> swizzled ds_read_b128 is uniform 8 dwords/bank.
  // global_load_lds: wave w call q stages chunks q*256 + w*64 + lane —
  // linear LDS dest (base = (q*256+w*64)*16 + lane*16), per-lane
  // PRE-SWIZZLED source. Source for chunk q*256+tid is srcb + q*4096
  // (swizzle preserved since (q*16 + g0) & 7 == g0 & 7).
  const int g0 = tid >> 4;
  const int sw = ((tid & 15) ^ (g0 & 7)) << 4;
  const char* srcb = zb + (size_t)(colBase0 + g0) * 256 + sw;

  char* ldsbase = (char*)&lds[0][0];
  const int wbase = wave * 1024;   // wave's LDS byte base within a q-slab

  // prologue: stage round 0 (async), then A frags, then drain at barrier
  #pragma unroll
  for (int q = 0; q < 4; q++)
    gl_lds16(srcb + q * 4096, ldsbase + q * 4096 + wbase);

  // A fragments: 4 row-tiles x 4 K-chunks (64 VGPRs) — full-line reads
  short8 a[4][4];
  #pragma unroll
  for (int t = 0; t < 4; t++) {
    const short* ap = zs + (size_t)(rowBase + t * 16 + l15) * DD + quad * 8;
    #pragma unroll
    for (int c = 0; c < 4; c++) a[t][c] = *(const short8*)(ap + c * 32);
  }

  float rs[4][4];
  #pragma unroll
  for (int t = 0; t < 4; t++)
    #pragma unroll
    for (int r = 0; r < 4; r++) rs[t][r] = 0.0f;

  __syncthreads();   // vmcnt(0) drain: round-0 tile resident

  int cur = 0;
  #pragma unroll 1
  for (int rd = 0; rd < NRD; rd++) {
    // issue next round's async loads into the spare buffer — safe: all
    // reads of it (round rd-1) finished before the barrier we passed.
    // Latency hides under this round's compute; end-of-round barrier
    // drains vmcnt.
    if (rd + 1 < NRD) {
      const char* sb = srcb + (size_t)(rd + 1) * (TW * 256);
      char* db = ldsbase + (cur ^ 1) * BUFBYTES + wbase;
      #pragma unroll
      for (int q = 0; q < 4; q++)
        gl_lds16(sb + q * 4096, db + q * 4096);
    }

    const char* lb = ldsbase + cur * BUFBYTES;
    #pragma unroll
    for (int k = 0; k < 4; k++) {           // 4 col-tiles per round
      short8 b[4];
      #pragma unroll
      for (int c = 0; c < 4; c++) {
        const int off = k * 4096 + l15 * 256 +
                        ((((c * 4 + quad) ^ (l15 & 7))) << 4);
        b[c] = *(const short8*)(lb + off);
      }
      #pragma unroll
      for (int t = 0; t < 4; t++) {
        float4v acc = {0.f, 0.f, 0.f, 0.f};
        acc = __builtin_amdgcn_mfma_f32_16x16x32_bf16(a[t][0], b[0], acc, 0, 0, 0);
        acc = __builtin_amdgcn_mfma_f32_16x16x32_bf16(a[t][1], b[1], acc, 0, 0, 0);
        acc = __builtin_amdgcn_mfma_f32_16x16x32_bf16(a[t][2], b[2], acc, 0, 0, 0);
        acc = __builtin_amdgcn_mfma_f32_16x16x32_bf16(a[t][3], b[3], acc, 0, 0, 0);
        // C/D: col = l15, row = quad*4 + r [m89/m91]; acc = 2log2e*sim.
        #pragma unroll
        for (int r = 0; r < 4; r++) rs[t][r] += EXP2F(acc[r]);
      }
    }

    if (rd + 1 < NRD) {
      __syncthreads();   // drains vmcnt (staged tile in LDS) + all waves done
      cur ^= 1;
    }
  }

  // reduce across the 16 lanes sharing each row, then one atomic each
  #pragma unroll
  for (int t = 0; t < 4; t++) {
    #pragma unroll
    for (int r = 0; r < 4; r++) {
      float s = rs[t][r];
      s += __shfl_xor(s, 1);
      s += __shfl_xor(s, 2);
      s += __shfl_xor(s, 4);
      s += __shfl_xor(s, 8);
      if (l15 == 0)
        atomicAdd(&rowsum[rowBase + t * 16 + quad * 4 + r], s);
    }
  }

  // ---- fused finalize ----
  __threadfence();                       // rowsum atomics visible
  if (tid == 0) lastPanel = atomicAdd(&panelCnt[blockIdx.y], 1u);
  __syncthreads();
  if (lastPanel == CSPLIT - 1) {
    // last block of this 256-row panel: finalize its rows
    const int r = blockIdx.y * 256 + tid;
    float rsv  = atomicAdd(&rowsum[r], 0.0f);   // coherent read
    float v = __logf(rsv) - 2.0f * pos[r];
    #pragma unroll
    for (int o = 32; o > 0; o >>= 1) v += __shfl_xor(v, o);
    if (lane == 0) psm[wave] = v;
    __syncthreads();
    if (tid == 0) {
      atomicAdd(accum, psm[0] + psm[1] + psm[2] + psm[3]);
    }
  }
  __threadfence();
  if (tid == 0) {
    unsigned int g = atomicAdd(globalCnt, 1u);
    if (g == NBLOCKS - 1) {              // last block overall
      out[0] = atomicAdd(accum, 0.0f) / (float)N2;
    }
  }
}

extern "C" void kernel_launch(void* const* d_in, const int* in_sizes, int n_in,
                              void* d_out, int out_size, void* d_ws, size_t ws_size,
                              hipStream_t stream) {
  const float* zi = (const float*)d_in[0];
  const float* zj = (const float*)d_in[1];
  float* out = (float*)d_out;

  char* ws = (char*)d_ws;
  bf16* zn = (bf16*)ws;                                   // 8192*128*2 = 2 MB
  float* rowsum = (float*)(ws + (size_t)N2 * DD * 2);     // 32 KB
  float* pos = rowsum + N2;                               // 32 KB
  float* accum = pos + N2;                                // 4 B
  unsigned int* panelCnt = (unsigned int*)(accum + 1);    // 128 B
  unsigned int* globalCnt = panelCnt + NPANEL;            // 4 B

  ntx_norm_kernel<<<BB / 4, 256, 0, stream>>>(zi, zj, zn, rowsum, pos,
                                              accum, panelCnt, globalCnt);
  dim3 grid(CSPLIT, NPANEL);
  ntx_sim_kernel<<<grid, 256, 0, stream>>>(zn, rowsum, pos, accum,
                                           panelCnt, globalCnt, out);
}

// Round 10
// 193.577 us; speedup vs baseline: 1.7876x; 1.6252x over previous
//
#include <hip/hip_runtime.h>
#include <hip/hip_bf16.h>

// NT-Xent loss: B=4096, D=128, TEMP=0.5, N2=8192.
// loss = mean_i [ log sum_{j!=i} exp(2*sim_ij) - 2*pos_i ]
// sim = zn zn^T (bf16 MFMA), pos_i = fp32 cosine(z_i, z_{i^B}).
// Self-diagonal handled by rowsum init = -exp2(sii_scaled).
//
// R10: R7/R9 proved __launch_bounds__(256,4) => 64-VGPR cap (empirically
// half the expected 128) => catastrophic scratch spill (FETCH/WRITE
// 100-200MB, sim 255-300us). New approach: no min-waves bound (no forced
// cap), and SHRINK the true live set instead: #pragma unroll 1 on the
// col-tile loop keeps only one b[4] batch (16 VGPRs) in flight instead of
// four (64). Static need ~115 -> compiler should land at the 128 boundary
// -> 4 waves/SIMD, all 1024 blocks resident in one pass. TLP (4 waves/
// SIMD) covers the lost cross-tile ds_read batching. Keep: async
// global_load_lds staging (linear LDS dest + pre-swizzled global src),
// one barrier per round, fused finalize via panel counters.

#define BB 4096
#define N2 8192
#define DD 128
#define CSPLIT 32          // column splits (grid.x)
#define CW (N2 / CSPLIT)   // 256 cols per block
#define TW 64              // cols staged per round (4 col-tiles, 16 KB)
#define NRD (CW / TW)      // 4 rounds
#define NPANEL 32          // row panels (grid.y)
#define NBLOCKS (CSPLIT * NPANEL)
#define BUFBYTES (TW * 16 * 16)   // 16384 B per LDS buffer

// sqrt(2*log2(e)): zn scaled by this => A.B = 2*log2(e)*sim, so
// exp(2*sim) = exp2(A.B) directly.
#define SCALE 1.69864360f

#if __has_builtin(__builtin_amdgcn_exp2f)
#define EXP2F(x) __builtin_amdgcn_exp2f(x)
#else
#define EXP2F(x) __expf((x) * 0.6931471805599453f)
#endif

using bf16 = __hip_bfloat16;
typedef __attribute__((ext_vector_type(8))) short short8;   // MFMA A/B frag
typedef __attribute__((ext_vector_type(4))) float float4v;  // MFMA C/D frag

// async 16B global->LDS (gfx950: global_load_lds_dwordx4).
// LDS dest is wave-uniform base + lane*16; global src is per-lane.
__device__ __forceinline__ void gl_lds16(const char* g, char* ldst) {
  __builtin_amdgcn_global_load_lds(
      (const __attribute__((address_space(1))) void*)g,
      (__attribute__((address_space(3))) void*)ldst, 16, 0, 0);
}

// ---------------- Kernel 1: per-pair normalize, scale, cast bf16 ----------
__global__ __launch_bounds__(256) void ntx_norm_kernel(
    const float* __restrict__ zi, const float* __restrict__ zj,
    bf16* __restrict__ zn, float* __restrict__ rowsum, float* __restrict__ pos,
    float* __restrict__ accum, unsigned int* __restrict__ panelCnt,
    unsigned int* __restrict__ globalCnt) {
  const int wave = threadIdx.x >> 6;
  const int lane = threadIdx.x & 63;
  // zero the sim kernel's completion counters (stream order makes this
  // visible before any sim block runs; ws is re-poisoned every replay)
  if (blockIdx.x == 0 && threadIdx.x < 34) {
    if (threadIdx.x < 32) panelCnt[threadIdx.x] = 0u;
    else if (threadIdx.x == 32) *globalCnt = 0u;
    else *accum = 0.0f;
  }
  const int pair = blockIdx.x * 4 + wave;   // 1024 blocks, 4 pairs/block
  float2 v = ((const float2*)(zi + (size_t)pair * DD))[lane];
  float2 w = ((const float2*)(zj + (size_t)pair * DD))[lane];
  float s1 = v.x * v.x + v.y * v.y;
  float s2 = w.x * w.x + w.y * w.y;
  float s3 = v.x * w.x + v.y * w.y;
  #pragma unroll
  for (int o = 32; o > 0; o >>= 1) {
    s1 += __shfl_xor(s1, o);
    s2 += __shfl_xor(s2, o);
    s3 += __shfl_xor(s3, o);
  }
  float nv = fmaxf(sqrtf(s1), 1e-8f);
  float nw = fmaxf(sqrtf(s2), 1e-8f);
  float rv = SCALE / nv, rw = SCALE / nw;   // scale folded into zn
  bf16 bx = __float2bfloat16(v.x * rv);
  bf16 by = __float2bfloat16(v.y * rv);
  bf16 cx = __float2bfloat16(w.x * rw);
  bf16 cy = __float2bfloat16(w.y * rw);
  __hip_bfloat162 h2; h2.x = bx; h2.y = by;
  __hip_bfloat162 g2; g2.x = cx; g2.y = cy;
  ((__hip_bfloat162*)(zn + (size_t)pair * DD))[lane] = h2;
  ((__hip_bfloat162*)(zn + (size_t)(pair + BB) * DD))[lane] = g2;
  // self-dot in the SAME scaled bf16 precision the MFMA will see
  float fx = __bfloat162float(bx), fy = __bfloat162float(by);
  float gx = __bfloat162float(cx), gy = __bfloat162float(cy);
  float sii = fx * fx + fy * fy;            // = 2log2e * sim_ii (scaled)
  float sjj = gx * gx + gy * gy;
  #pragma unroll
  for (int o = 32; o > 0; o >>= 1) {
    sii += __shfl_xor(sii, o);
    sjj += __shfl_xor(sjj, o);
  }
  if (lane == 0) {
    float c = s3 / (nv * nw);               // fp32 positive-pair cosine
    rowsum[pair]      = -EXP2F(sii);        // cancels diagonal term
    rowsum[pair + BB] = -EXP2F(sjj);
    pos[pair]      = c;
    pos[pair + BB] = c;
  }
}

// ---------------- Kernel 2: fused sim + sum-exp + finalize -----------------
// grid (CSPLIT=32, 32). Block 256 = 4 waves; wave owns 64 rows (4 row-tiles),
// block owns 256 rows x 256 cols. Per round: issue async global_load_lds of
// the next 64 cols (16 KB) into the spare buffer, compute 4 col-tiles from
// the current buffer (rolled loop — one b-batch live), ONE barrier, flip.
// Tail: panel-last block finalizes its 256 rows; global-last writes out.
__global__ __launch_bounds__(256) void ntx_sim_kernel(
    const bf16* __restrict__ zn, float* __restrict__ rowsum,
    const float* __restrict__ pos, float* __restrict__ accum,
    unsigned int* __restrict__ panelCnt, unsigned int* __restrict__ globalCnt,
    float* __restrict__ out) {
  const int tid  = threadIdx.x;
  const int wave = tid >> 6;
  const int lane = tid & 63;
  const int quad = lane >> 4;
  const int l15  = lane & 15;
  const char* zb  = (const char*)zn;
  const short* zs = (const short*)zn;

  __shared__ float4 lds[2][TW * 16];   // 2 x 16 KB double buffer
  __shared__ float psm[4];
  __shared__ unsigned int lastPanel;

  const int rowBase  = blockIdx.y * 256 + wave * 64;
  const int colBase0 = blockIdx.x * CW;

  // Staging map: 1024 chunks of 16B per round; chunk c lives at LDS byte
  // c*16 and holds global 16B-chunk (slot ^ (g&7)) of col-row g (g = c>>4,
  // slot = c&15) -> swizzled ds_read_b128 is uniform 8 dwords/bank.
  // global_load_lds: wave w call q stages chunks q*256 + w*64 + lane —
  // linear LDS dest, per-lane PRE-SWIZZLED source (m173 pattern).
  const int g0 = tid >> 4;
  const int sw = ((tid & 15) ^ (g0 & 7)) << 4;
  const char* srcb = zb + (size_t)(colBase0 + g0) * 256 + sw;

  char* ldsbase = (char*)&lds[0][0];
  const int wbase = wave * 1024;   // wave's LDS byte base within a q-slab

  // prologue: stage round 0 (async), then A frags, then drain at barrier
  #pragma unroll
  for (int q = 0; q < 4; q++)
    gl_lds16(srcb + q * 4096, ldsbase + q * 4096 + wbase);

  // A fragments: 4 row-tiles x 4 K-chunks (64 VGPRs) — full-line reads
  short8 a[4][4];
  #pragma unroll
  for (int t = 0; t < 4; t++) {
    const short* ap = zs + (size_t)(rowBase + t * 16 + l15) * DD + quad * 8;
    #pragma unroll
    for (int c = 0; c < 4; c++) a[t][c] = *(const short8*)(ap + c * 32);
  }

  float rs[4][4];
  #pragma unroll
  for (int t = 0; t < 4; t++)
    #pragma unroll
    for (int r = 0; r < 4; r++) rs[t][r] = 0.0f;

  __syncthreads();   // vmcnt(0) drain: round-0 tile resident

  int cur = 0;
  #pragma unroll 1
  for (int rd = 0; rd < NRD; rd++) {
    // issue next round's async loads into the spare buffer — safe: all
    // reads of it (round rd-1) finished before the barrier we passed.
    if (rd + 1 < NRD) {
      const char* sb = srcb + (size_t)(rd + 1) * (TW * 256);
      char* db = ldsbase + (cur ^ 1) * BUFBYTES + wbase;
      #pragma unroll
      for (int q = 0; q < 4; q++)
        gl_lds16(sb + q * 4096, db + q * 4096);
    }

    const char* lb = ldsbase + cur * BUFBYTES;
    #pragma unroll 1
    for (int k = 0; k < 4; k++) {           // ROLLED: one b[4] batch live
      short8 b[4];
      #pragma unroll
      for (int c = 0; c < 4; c++) {
        const int off = k * 4096 + l15 * 256 +
                        ((((c * 4 + quad) ^ (l15 & 7))) << 4);
        b[c] = *(const short8*)(lb + off);
      }
      #pragma unroll
      for (int t = 0; t < 4; t++) {
        float4v acc = {0.f, 0.f, 0.f, 0.f};
        acc = __builtin_amdgcn_mfma_f32_16x16x32_bf16(a[t][0], b[0], acc, 0, 0, 0);
        acc = __builtin_amdgcn_mfma_f32_16x16x32_bf16(a[t][1], b[1], acc, 0, 0, 0);
        acc = __builtin_amdgcn_mfma_f32_16x16x32_bf16(a[t][2], b[2], acc, 0, 0, 0);
        acc = __builtin_amdgcn_mfma_f32_16x16x32_bf16(a[t][3], b[3], acc, 0, 0, 0);
        // C/D: col = l15, row = quad*4 + r [m89/m91]; acc = 2log2e*sim.
        #pragma unroll
        for (int r = 0; r < 4; r++) rs[t][r] += EXP2F(acc[r]);
      }
    }

    if (rd + 1 < NRD) {
      __syncthreads();   // drains vmcnt (staged tile in LDS) + all waves done
      cur ^= 1;
    }
  }

  // reduce across the 16 lanes sharing each row, then one atomic each
  #pragma unroll
  for (int t = 0; t < 4; t++) {
    #pragma unroll
    for (int r = 0; r < 4; r++) {
      float s = rs[t][r];
      s += __shfl_xor(s, 1);
      s += __shfl_xor(s, 2);
      s += __shfl_xor(s, 4);
      s += __shfl_xor(s, 8);
      if (l15 == 0)
        atomicAdd(&rowsum[rowBase + t * 16 + quad * 4 + r], s);
    }
  }

  // ---- fused finalize ----
  __threadfence();                       // rowsum atomics visible
  if (tid == 0) lastPanel = atomicAdd(&panelCnt[blockIdx.y], 1u);
  __syncthreads();
  if (lastPanel == CSPLIT - 1) {
    // last block of this 256-row panel: finalize its rows
    const int r = blockIdx.y * 256 + tid;
    float rsv  = atomicAdd(&rowsum[r], 0.0f);   // coherent read
    float v = __logf(rsv) - 2.0f * pos[r];
    #pragma unroll
    for (int o = 32; o > 0; o >>= 1) v += __shfl_xor(v, o);
    if (lane == 0) psm[wave] = v;
    __syncthreads();
    if (tid == 0) {
      atomicAdd(accum, psm[0] + psm[1] + psm[2] + psm[3]);
    }
  }
  __threadfence();
  if (tid == 0) {
    unsigned int g = atomicAdd(globalCnt, 1u);
    if (g == NBLOCKS - 1) {              // last block overall
      out[0] = atomicAdd(accum, 0.0f) / (float)N2;
    }
  }
}

extern "C" void kernel_launch(void* const* d_in, const int* in_sizes, int n_in,
                              void* d_out, int out_size, void* d_ws, size_t ws_size,
                              hipStream_t stream) {
  const float* zi = (const float*)d_in[0];
  const float* zj = (const float*)d_in[1];
  float* out = (float*)d_out;

  char* ws = (char*)d_ws;
  bf16* zn = (bf16*)ws;                                   // 8192*128*2 = 2 MB
  float* rowsum = (float*)(ws + (size_t)N2 * DD * 2);     // 32 KB
  float* pos = rowsum + N2;                               // 32 KB
  float* accum = pos + N2;                                // 4 B
  unsigned int* panelCnt = (unsigned int*)(accum + 1);    // 128 B
  unsigned int* globalCnt = panelCnt + NPANEL;            // 4 B

  ntx_norm_kernel<<<BB / 4, 256, 0, stream>>>(zi, zj, zn, rowsum, pos,
                                              accum, panelCnt, globalCnt);
  dim3 grid(CSPLIT, NPANEL);
  ntx_sim_kernel<<<grid, 256, 0, stream>>>(zn, rowsum, pos, accum,
                                           panelCnt, globalCnt, out);
}

// Round 11
// 90.121 us; speedup vs baseline: 3.8397x; 2.1480x over previous
//
#include <hip/hip_runtime.h>
#include <hip/hip_bf16.h>

// NT-Xent loss: B=4096, D=128, TEMP=0.5, N2=8192.
// loss = mean_i [ log sum_{j!=i} exp(2*sim_ij) - 2*pos_i ]
// sim = zn zn^T (bf16 MFMA), pos_i = fp32 cosine(z_i, z_{i^B}).
// Self-diagonal handled by rowsum init = -exp2(sii_scaled).
//
// R11: R10's counters caught the real pathology: VGPR_Count=60 < the 64
// VGPRs of a[4][4] alone -> the compiler RELOADED the A-fragments from
// global every k-iteration (L2-hit latency fully exposed; MfmaUtil 4.7%).
// The rolled k-loop triggered it; (256,4) launch bounds force the same
// starvation plus scratch spill (R7/R9). Fix: revert to the proven R6
// structure (reg staging, TW=64, 1 barrier/round, unrolled k, separate
// finalize; 91.8us) + pin the 16 A-fragments live with an empty
// asm "+v" (rule #17) so the allocator can never drop them. True live
// set ~120 VGPR <= 128 -> 4 waves/SIMD with no cliff risk.

#define BB 4096
#define N2 8192
#define DD 128
#define CSPLIT 32          // column splits (grid.x)
#define CW (N2 / CSPLIT)   // 256 cols per block
#define TW 64              // cols staged per round (4 col-tiles, 16 KB)
#define NRD (CW / TW)      // 4 rounds

// sqrt(2*log2(e)): zn scaled by this => A.B = 2*log2(e)*sim, so
// exp(2*sim) = exp2(A.B) directly.
#define SCALE 1.69864360f

#if __has_builtin(__builtin_amdgcn_exp2f)
#define EXP2F(x) __builtin_amdgcn_exp2f(x)
#else
#define EXP2F(x) __expf((x) * 0.6931471805599453f)
#endif

using bf16 = __hip_bfloat16;
typedef __attribute__((ext_vector_type(8))) short short8;   // MFMA A/B frag
typedef __attribute__((ext_vector_type(4))) float float4v;  // MFMA C/D frag

// ---------------- Kernel 1: per-pair normalize, scale, cast bf16 ----------
__global__ __launch_bounds__(256) void ntx_norm_kernel(
    const float* __restrict__ zi, const float* __restrict__ zj,
    bf16* __restrict__ zn, float* __restrict__ rowsum, float* __restrict__ pos) {
  const int wave = threadIdx.x >> 6;
  const int lane = threadIdx.x & 63;
  const int pair = blockIdx.x * 4 + wave;   // 1024 blocks, 4 pairs/block
  float2 v = ((const float2*)(zi + (size_t)pair * DD))[lane];
  float2 w = ((const float2*)(zj + (size_t)pair * DD))[lane];
  float s1 = v.x * v.x + v.y * v.y;
  float s2 = w.x * w.x + w.y * w.y;
  float s3 = v.x * w.x + v.y * w.y;
  #pragma unroll
  for (int o = 32; o > 0; o >>= 1) {
    s1 += __shfl_xor(s1, o);
    s2 += __shfl_xor(s2, o);
    s3 += __shfl_xor(s3, o);
  }
  float nv = fmaxf(sqrtf(s1), 1e-8f);
  float nw = fmaxf(sqrtf(s2), 1e-8f);
  float rv = SCALE / nv, rw = SCALE / nw;   // scale folded into zn
  bf16 bx = __float2bfloat16(v.x * rv);
  bf16 by = __float2bfloat16(v.y * rv);
  bf16 cx = __float2bfloat16(w.x * rw);
  bf16 cy = __float2bfloat16(w.y * rw);
  __hip_bfloat162 h2; h2.x = bx; h2.y = by;
  __hip_bfloat162 g2; g2.x = cx; g2.y = cy;
  ((__hip_bfloat162*)(zn + (size_t)pair * DD))[lane] = h2;
  ((__hip_bfloat162*)(zn + (size_t)(pair + BB) * DD))[lane] = g2;
  // self-dot in the SAME scaled bf16 precision the MFMA will see
  float fx = __bfloat162float(bx), fy = __bfloat162float(by);
  float gx = __bfloat162float(cx), gy = __bfloat162float(cy);
  float sii = fx * fx + fy * fy;            // = 2log2e * sim_ii (scaled)
  float sjj = gx * gx + gy * gy;
  #pragma unroll
  for (int o = 32; o > 0; o >>= 1) {
    sii += __shfl_xor(sii, o);
    sjj += __shfl_xor(sjj, o);
  }
  if (lane == 0) {
    float c = s3 / (nv * nw);               // fp32 positive-pair cosine
    rowsum[pair]      = -EXP2F(sii);        // cancels diagonal term
    rowsum[pair + BB] = -EXP2F(sjj);
    pos[pair]      = c;
    pos[pair + BB] = c;
  }
}

// ---------------- Kernel 2: fused sim + sum-exp ----------------------------
// grid (CSPLIT=32, 32). Block 256 = 4 waves; wave owns 64 rows (4 row-tiles),
// block owns 256 rows x 256 cols. Per round: stage 64 cols (16 KB) of B into
// the spare LDS buffer (coalesced, pre-swizzled source, loads issued EARLY),
// compute 4 col-tiles from the current buffer, ONE barrier, flip.
__global__ __launch_bounds__(256) void ntx_sim_kernel(
    const bf16* __restrict__ zn, float* __restrict__ rowsum) {
  const int tid  = threadIdx.x;
  const int wave = tid >> 6;
  const int lane = tid & 63;
  const int quad = lane >> 4;
  const int l15  = lane & 15;
  const char* zb  = (const char*)zn;
  const short* zs = (const short*)zn;

  __shared__ float4 lds[2][TW * 16];   // 2 x 16 KB double buffer

  const int rowBase  = blockIdx.y * 256 + wave * 64;
  const int colBase0 = blockIdx.x * CW;

  // Staging map: 1024 chunks of 16B per round; thread owns chunks
  // tid + q*256 (q=0..3). Chunk p: col-row g = p>>4, slot = p&15.
  // LDS[g][slot] holds global chunk (slot ^ (g&7)) of col-row g
  // -> swizzled ds_read_b128 is uniform 8 dwords/bank (optimal).
  // q-step is +16 rows = +4096 B in BOTH src and dst (g&7 unchanged).
  const int g0 = tid >> 4;
  const int sw = ((tid & 15) ^ (g0 & 7)) << 4;
  const char* srcb = zb + (size_t)(colBase0 + g0) * 256 + sw;

  // prologue: stage round 0
  float4 p0 = *(const float4*)(srcb);
  float4 p1 = *(const float4*)(srcb + 4096);
  float4 p2 = *(const float4*)(srcb + 8192);
  float4 p3 = *(const float4*)(srcb + 12288);

  // A fragments: 4 row-tiles x 4 K-chunks (64 VGPRs) — full-line reads
  short8 a[4][4];
  #pragma unroll
  for (int t = 0; t < 4; t++) {
    const short* ap = zs + (size_t)(rowBase + t * 16 + l15) * DD + quad * 8;
    #pragma unroll
    for (int c = 0; c < 4; c++) a[t][c] = *(const short8*)(ap + c * 32);
  }
  // PIN A resident (rule #17): R10 showed the allocator may drop a[][] and
  // re-load from global inside the loop (VGPR_Count 60 < 64). The empty
  // asm with "+v" forces all 16 fragments to live in VGPRs here.
  asm volatile("" : "+v"(a[0][0]), "+v"(a[0][1]), "+v"(a[0][2]), "+v"(a[0][3]),
                    "+v"(a[1][0]), "+v"(a[1][1]), "+v"(a[1][2]), "+v"(a[1][3]),
                    "+v"(a[2][0]), "+v"(a[2][1]), "+v"(a[2][2]), "+v"(a[2][3]),
                    "+v"(a[3][0]), "+v"(a[3][1]), "+v"(a[3][2]), "+v"(a[3][3]));

  float rs[4][4];
  #pragma unroll
  for (int t = 0; t < 4; t++)
    #pragma unroll
    for (int r = 0; r < 4; r++) rs[t][r] = 0.0f;

  lds[0][tid] = p0;
  lds[0][tid + 256] = p1;
  lds[0][tid + 512] = p2;
  lds[0][tid + 768] = p3;
  __syncthreads();

  int cur = 0;
  #pragma unroll 1
  for (int rd = 0; rd < NRD; rd++) {
    // issue next round's loads EARLY — latency hides under this round
    float4 t0, t1, t2, t3;
    const bool pf = (rd + 1 < NRD);
    if (pf) {
      const char* sb = srcb + (size_t)(rd + 1) * (TW * 256);
      t0 = *(const float4*)(sb);
      t1 = *(const float4*)(sb + 4096);
      t2 = *(const float4*)(sb + 8192);
      t3 = *(const float4*)(sb + 12288);
    }

    const char* lb = (const char*)&lds[cur][0];
    #pragma unroll
    for (int k = 0; k < 4; k++) {           // 4 col-tiles per round
      short8 b[4];
      #pragma unroll
      for (int c = 0; c < 4; c++) {
        const int off = k * 4096 + l15 * 256 +
                        ((((c * 4 + quad) ^ (l15 & 7))) << 4);
        b[c] = *(const short8*)(lb + off);
      }
      #pragma unroll
      for (int t = 0; t < 4; t++) {
        float4v acc = {0.f, 0.f, 0.f, 0.f};
        acc = __builtin_amdgcn_mfma_f32_16x16x32_bf16(a[t][0], b[0], acc, 0, 0, 0);
        acc = __builtin_amdgcn_mfma_f32_16x16x32_bf16(a[t][1], b[1], acc, 0, 0, 0);
        acc = __builtin_amdgcn_mfma_f32_16x16x32_bf16(a[t][2], b[2], acc, 0, 0, 0);
        acc = __builtin_amdgcn_mfma_f32_16x16x32_bf16(a[t][3], b[3], acc, 0, 0, 0);
        // C/D: col = l15, row = quad*4 + r [m89/m91]; acc = 2log2e*sim.
        #pragma unroll
        for (int r = 0; r < 4; r++) rs[t][r] += EXP2F(acc[r]);
      }
    }

    if (pf) {
      // write buf[cur^1]: safe — every wave passed the previous barrier,
      // so all reads of buf[cur^1] (round rd-1) completed. One barrier.
      lds[cur ^ 1][tid] = t0;
      lds[cur ^ 1][tid + 256] = t1;
      lds[cur ^ 1][tid + 512] = t2;
      lds[cur ^ 1][tid + 768] = t3;
      __syncthreads();
      cur ^= 1;
    }
  }

  // reduce across the 16 lanes sharing each row, then one atomic each
  #pragma unroll
  for (int t = 0; t < 4; t++) {
    #pragma unroll
    for (int r = 0; r < 4; r++) {
      float s = rs[t][r];
      s += __shfl_xor(s, 1);
      s += __shfl_xor(s, 2);
      s += __shfl_xor(s, 4);
      s += __shfl_xor(s, 8);
      if (l15 == 0)
        atomicAdd(&rowsum[rowBase + t * 16 + quad * 4 + r], s);
    }
  }
}

// ---------------- Kernel 3: finalize --------------------------------------
__global__ __launch_bounds__(1024) void ntx_finalize_kernel(
    const float* __restrict__ rowsum, const float* __restrict__ pos,
    float* __restrict__ out) {
  float s = 0.f;
  for (int i = threadIdx.x; i < N2; i += 1024)
    s += __logf(rowsum[i]) - 2.0f * pos[i];
  #pragma unroll
  for (int o = 32; o > 0; o >>= 1) s += __shfl_xor(s, o);
  __shared__ float sm[16];
  const int wave = threadIdx.x >> 6;
  const int lane = threadIdx.x & 63;
  if (lane == 0) sm[wave] = s;
  __syncthreads();
  if (threadIdx.x == 0) {
    float t = 0.f;
    #pragma unroll
    for (int i = 0; i < 16; i++) t += sm[i];
    out[0] = t / (float)N2;
  }
}

extern "C" void kernel_launch(void* const* d_in, const int* in_sizes, int n_in,
                              void* d_out, int out_size, void* d_ws, size_t ws_size,
                              hipStream_t stream) {
  const float* zi = (const float*)d_in[0];
  const float* zj = (const float*)d_in[1];
  float* out = (float*)d_out;

  char* ws = (char*)d_ws;
  bf16* zn = (bf16*)ws;                                   // 8192*128*2 = 2 MB
  float* rowsum = (float*)(ws + (size_t)N2 * DD * 2);     // 32 KB
  float* pos = rowsum + N2;                               // 32 KB

  ntx_norm_kernel<<<BB / 4, 256, 0, stream>>>(zi, zj, zn, rowsum, pos);
  dim3 grid(CSPLIT, N2 / 256);
  ntx_sim_kernel<<<grid, 256, 0, stream>>>(zn, rowsum);
  ntx_finalize_kernel<<<1, 1024, 0, stream>>>(rowsum, pos, out);
}